// Round 22
// baseline (402.329 us; speedup 1.0000x reference)
//
#include <hip/hip_runtime.h>
#include <math.h>

#define B_ 2
#define H_ 16
#define L_ 2048
#define D_ 64
#define OUT_ELEMS ((size_t)B_ * H_ * L_ * D_)
#define WPR (L_ / 16)               // 128 mask-words per row
// SCALE * log2(e): scores computed directly in exp2 domain
#define C1 0.180336880f

typedef _Float16 half8 __attribute__((ext_vector_type(8)));
typedef _Float16 half4_t __attribute__((ext_vector_type(4)));
typedef float f32x4 __attribute__((ext_vector_type(4)));
typedef int i32x4 __attribute__((ext_vector_type(4)));
typedef unsigned int u32;
typedef unsigned short u16;
typedef u16 u16x4 __attribute__((ext_vector_type(4)));
typedef u32 u32x4 __attribute__((ext_vector_type(4)));
typedef u32 u32x2 __attribute__((ext_vector_type(2)));

// T2 XOR swizzle: 16B-slot permute within a 128B row (colh in halves)
#define SWZ(row, colh) ((colh) ^ (((row) & 7) << 3))

// ---------------- K0: pack mask -> 1 bit/element (1 MB table) ----------------
__global__ __launch_bounds__(256) void pack_kernel(
    const int* __restrict__ M, u16* __restrict__ pmask)
{
  const int idx = blockIdx.x * 256 + threadIdx.x;
  const int* src = M + (size_t)idx * 16;
  u32 w = 0;
#pragma unroll
  for (int j = 0; j < 4; ++j) {
    i32x4 m = ((const i32x4*)src)[j];
#pragma unroll
    for (int r = 0; r < 4; ++r)
      w |= (m[r] != 0 ? 1u : 0u) << (j * 4 + r);
  }
  pmask[idx] = (u16)w;
}

// -------- K1: flat-softmax denominators, k-split x4 --------
// NEW: K fragments loaded DIRECTLY global->reg->MFMA (all 4 waves read the
// same frags; K is L2-resident via XCD swizzle). Zero LDS, zero barriers;
// 8 blocks/CU, TLP hides all load latency.
__global__ __launch_bounds__(256, 8) void lsum_kernel(
    const float* __restrict__ Q, const float* __restrict__ K,
    const u16* __restrict__ pmask, float* __restrict__ lpart)
{
  const int qt = blockIdx.x, h = blockIdx.y;
  const int b = blockIdx.z >> 2, kq = blockIdx.z & 3;
  const int bh = b * H_ + h;
  const int q0 = qt * 64, k0 = kq * 512;
  const int tid = threadIdx.x;
  const int wv = tid >> 6, lane = tid & 63;
  const int lr = lane & 15, lg = lane >> 4;
  const int qrow = q0 + wv * 16 + lr;

  const float* kbase = K + ((size_t)bh * L_ + k0) * D_;
  const u16* pmrow = pmask + (size_t)(b * L_ + qrow) * WPR + (k0 >> 4);

  half8 qf[2];
  {
    const float* qr = Q + (size_t)(bh * L_ + qrow) * D_;
#pragma unroll
    for (int f = 0; f < 2; ++f) {
      f32x4 x = *(const f32x4*)(qr + f * 32 + lg * 8);
      f32x4 y = *(const f32x4*)(qr + f * 32 + lg * 8 + 4);
      qf[f] = half8{(_Float16)(x[0]*C1), (_Float16)(x[1]*C1), (_Float16)(x[2]*C1), (_Float16)(x[3]*C1),
                    (_Float16)(y[0]*C1), (_Float16)(y[1]*C1), (_Float16)(y[2]*C1), (_Float16)(y[3]*C1)};
    }
  }

  float l_l = 0.f;

  for (int c = 0; c < 8; ++c) {
    const int kc = c * 64;
    u16x4 pm = *(const u16x4*)(pmrow + c * 4);

    f32x4 acc[4] = {f32x4{0,0,0,0}, f32x4{0,0,0,0}, f32x4{0,0,0,0}, f32x4{0,0,0,0}};
#pragma unroll
    for (int kb = 0; kb < 4; ++kb) {
      // lane's A-frag: K[kc+kb*16+lr][f*32 + lg*8 .. +7] (32B contiguous)
      const float* kp = kbase + (size_t)(kc + kb * 16 + lr) * D_ + lg * 8;
      f32x4 x0 = ((const f32x4*)kp)[0];
      f32x4 x1 = ((const f32x4*)kp)[1];
      f32x4 y0 = ((const f32x4*)(kp + 32))[0];
      f32x4 y1 = ((const f32x4*)(kp + 32))[1];
      half8 a0 = half8{(_Float16)x0[0], (_Float16)x0[1], (_Float16)x0[2], (_Float16)x0[3],
                       (_Float16)x1[0], (_Float16)x1[1], (_Float16)x1[2], (_Float16)x1[3]};
      half8 a1 = half8{(_Float16)y0[0], (_Float16)y0[1], (_Float16)y0[2], (_Float16)y0[3],
                       (_Float16)y1[0], (_Float16)y1[1], (_Float16)y1[2], (_Float16)y1[3]};
      acc[kb] = __builtin_amdgcn_mfma_f32_16x16x32_f16(a0, qf[0], acc[kb], 0, 0, 0);
      acc[kb] = __builtin_amdgcn_mfma_f32_16x16x32_f16(a1, qf[1], acc[kb], 0, 0, 0);
    }

    float cs = 0.f;
#pragma unroll
    for (int kb = 0; kb < 4; ++kb)
#pragma unroll
      for (int r = 0; r < 4; ++r)
        cs += exp2f(((pm[kb] >> (lg * 4 + r)) & 1) ? acc[kb][r] : -INFINITY);
    l_l += cs;
  }

  l_l += __shfl_xor(l_l, 16);
  l_l += __shfl_xor(l_l, 32);
  if (lg == 0)
    lpart[((size_t)kq * 32 + bh) * L_ + qrow] = l_l;
}

// ------- K2 device body: score via LDS-coalesced NT stores + O partial -------
// Double-buffered K/V register prefetch. P tile bounced through swizzled Pbuf;
// each WAVE stores its OWN 16 rows (256B contiguous per row).
template <int KCH>
__device__ __forceinline__ void attn_body(
    const float* Q, const float* K, const float* V,
    const u16* pmask, const float* lpart,
    float* obase, float* score, int b, int h, int qt, int k0)
{
  const int bh = b * H_ + h;
  const int q0 = qt * 64;
  const int tid = threadIdx.x;
  const int wv = tid >> 6, lane = tid & 63;
  const int lr = lane & 15, lg = lane >> 4;
  const int qrow = q0 + wv * 16 + lr;

  __shared__ _Float16 Klds[64 * 64];   // 8KB, XOR-swizzled
  __shared__ _Float16 Vlds[64 * 64];   // 8KB, XOR-swizzled
  __shared__ float Pbuf[64 * 68];      // 17KB, 17 f32x4-slots/row, swizzled

  const float* kbase = K + ((size_t)bh * L_ + k0) * D_;
  const float* vbase = V + ((size_t)bh * L_ + k0) * D_;
  const u16* pmrow = pmask + (size_t)(b * L_ + qrow) * WPR + (k0 >> 4);
  float* sbase = score + ((size_t)bh * L_ + q0) * L_ + k0;
  float* ob = obase + (size_t)(bh * L_ + q0) * D_;

  float lsum = 0.f;
#pragma unroll
  for (int kq = 0; kq < 4; ++kq)
    lsum += lpart[((size_t)kq * 32 + bh) * L_ + qrow];
  const float inv_l = (lsum > 0.f) ? 1.f / lsum : 0.f;

  half8 qf[2];
  {
    const float* qr = Q + (size_t)(bh * L_ + qrow) * D_;
#pragma unroll
    for (int f = 0; f < 2; ++f) {
      f32x4 x = *(const f32x4*)(qr + f * 32 + lg * 8);
      f32x4 y = *(const f32x4*)(qr + f * 32 + lg * 8 + 4);
      qf[f] = half8{(_Float16)(x[0]*C1), (_Float16)(x[1]*C1), (_Float16)(x[2]*C1), (_Float16)(x[3]*C1),
                    (_Float16)(y[0]*C1), (_Float16)(y[1]*C1), (_Float16)(y[2]*C1), (_Float16)(y[3]*C1)};
    }
  }

  const int ksr = tid >> 2, ksd = (tid & 3) * 16;
  const int vk0 = (tid & 15) * 4, vd0 = (tid >> 4) * 4;

  auto loadK4 = [&](int kc, f32x4* r) {
    const float* s = kbase + (size_t)(kc + ksr) * D_ + ksd;
    r[0] = ((const f32x4*)s)[0]; r[1] = ((const f32x4*)s)[1];
    r[2] = ((const f32x4*)s)[2]; r[3] = ((const f32x4*)s)[3];
  };
  auto writeK = [&](const f32x4* r) {
    half8 lo = half8{(_Float16)r[0][0], (_Float16)r[0][1], (_Float16)r[0][2], (_Float16)r[0][3],
                     (_Float16)r[1][0], (_Float16)r[1][1], (_Float16)r[1][2], (_Float16)r[1][3]};
    half8 hi = half8{(_Float16)r[2][0], (_Float16)r[2][1], (_Float16)r[2][2], (_Float16)r[2][3],
                     (_Float16)r[3][0], (_Float16)r[3][1], (_Float16)r[3][2], (_Float16)r[3][3]};
    *(half8*)&Klds[(ksr << 6) + SWZ(ksr, ksd)] = lo;
    *(half8*)&Klds[(ksr << 6) + SWZ(ksr, ksd + 8)] = hi;
  };
  auto loadV4 = [&](int kc, f32x4* r) {
#pragma unroll
    for (int i = 0; i < 4; ++i)
      r[i] = *(const f32x4*)(vbase + (size_t)(kc + vk0 + i) * D_ + vd0);
  };
  auto writeV = [&](const f32x4* r) {
#pragma unroll
    for (int j = 0; j < 4; ++j) {
      int row = vd0 + j;
      *(half4_t*)&Vlds[(row << 6) + SWZ(row, vk0)] =
          half4_t{(_Float16)r[0][j], (_Float16)r[1][j],
                  (_Float16)r[2][j], (_Float16)r[3][j]};
    }
  };

  {
    f32x4 kr[4], vr[4];
    loadK4(0, kr); loadV4(0, vr);
    writeK(kr); writeV(vr);
  }
  __syncthreads();

  f32x4 o_acc[4] = {f32x4{0,0,0,0}, f32x4{0,0,0,0}, f32x4{0,0,0,0}, f32x4{0,0,0,0}};
  f32x4 krP[4], vrP[4];

  const int s0lane = lr + 32 * (lg & 1);
  const int s1lane = s0lane + 16;
  const bool hisel = (lg & 2) != 0;

  for (int c = 0; c < KCH; ++c) {
    const int kc = c * 64;
    if (c > 0) {
      __syncthreads();            // K/V readers of chunk c-1 done
      writeK(krP);
      writeV(vrP);
      __syncthreads();            // chunk c staged
    }
    // prefetch next chunk into registers (consumed at next iter's top)
    if (c < KCH - 1) {
      loadK4(kc + 64, krP);
      loadV4(kc + 64, vrP);
    }
    u16x4 pm = *(const u16x4*)(pmrow + c * 4);

    f32x4 acc[4] = {f32x4{0,0,0,0}, f32x4{0,0,0,0}, f32x4{0,0,0,0}, f32x4{0,0,0,0}};
    __builtin_amdgcn_s_setprio(1);
#pragma unroll
    for (int kb = 0; kb < 4; ++kb) {
      int row = kb * 16 + lr;
      half8 a0 = *(const half8*)&Klds[(row << 6) + SWZ(row, lg * 8)];
      half8 a1 = *(const half8*)&Klds[(row << 6) + SWZ(row, 32 + lg * 8)];
      acc[kb] = __builtin_amdgcn_mfma_f32_16x16x32_f16(a0, qf[0], acc[kb], 0, 0, 0);
      acc[kb] = __builtin_amdgcn_mfma_f32_16x16x32_f16(a1, qf[1], acc[kb], 0, 0, 0);
    }
    __builtin_amdgcn_s_setprio(0);

    // P = exp2(s)/l ; stash fp32 tile in swizzled Pbuf; pack halves for PV
    u32 phu[8];
    const int prow = wv * 16 + lr;
#pragma unroll
    for (int kb = 0; kb < 4; ++kb) {
      f32x4 p4;
#pragma unroll
      for (int r = 0; r < 4; ++r)
        p4[r] = exp2f(((pm[kb] >> (lg * 4 + r)) & 1) ? acc[kb][r] : -INFINITY) * inv_l;
      int pslot = (kb * 4 + lg) ^ (prow & 7);           // 16B-slot swizzle
      *(f32x4*)&Pbuf[prow * 68 + pslot * 4] = p4;
      half4_t hp = half4_t{(_Float16)p4[0], (_Float16)p4[1],
                           (_Float16)p4[2], (_Float16)p4[3]};
      u32x2 uu = __builtin_bit_cast(u32x2, hp);
      phu[2 * kb] = uu[0];
      phu[2 * kb + 1] = uu[1];
    }

    // Redistribute P via shuffles; PV MFMA
    __builtin_amdgcn_s_setprio(1);
#pragma unroll
    for (int ks = 0; ks < 2; ++ks) {
      int a0 = __shfl((int)phu[4 * ks + 0], s0lane);
      int a1 = __shfl((int)phu[4 * ks + 1], s0lane);
      int a2 = __shfl((int)phu[4 * ks + 2], s0lane);
      int a3 = __shfl((int)phu[4 * ks + 3], s0lane);
      int b0 = __shfl((int)phu[4 * ks + 0], s1lane);
      int b1 = __shfl((int)phu[4 * ks + 1], s1lane);
      int b2 = __shfl((int)phu[4 * ks + 2], s1lane);
      int b3 = __shfl((int)phu[4 * ks + 3], s1lane);
      u32x4 pau = u32x4{(u32)(hisel ? a2 : a0), (u32)(hisel ? a3 : a1),
                        (u32)(hisel ? b2 : b0), (u32)(hisel ? b3 : b1)};
      half8 pa = __builtin_bit_cast(half8, pau);
#pragma unroll
      for (int db = 0; db < 4; ++db) {
        int row = db * 16 + lr;
        half8 vf = *(const half8*)&Vlds[(row << 6) + SWZ(row, ks * 32 + lg * 8)];
        o_acc[db] = __builtin_amdgcn_mfma_f32_16x16x32_f16(pa, vf, o_acc[db], 0, 0, 0);
      }
    }
    __builtin_amdgcn_s_setprio(0);

    // ---- per-wave coalesced score store (no barrier: own rows only) ----
#pragma unroll
    for (int it = 0; it < 4; ++it) {
      int row = wv * 16 + it * 4 + (lane >> 4);
      int slot = (lane & 15) ^ (row & 7);               // un-swizzle
      f32x4 v = *(const f32x4*)&Pbuf[row * 68 + slot * 4];
      __builtin_nontemporal_store(
          v, (f32x4*)(sbase + (size_t)row * L_ + kc + (lane & 15) * 4));
    }
  }

#pragma unroll
  for (int db = 0; db < 4; ++db)
#pragma unroll
    for (int r = 0; r < 4; ++r)
      ob[(size_t)(wv * 16 + lg * 4 + r) * D_ + db * 16 + lr] = o_acc[db][r];
}

// ---- K2a: split main kernel (2048 blocks, k-half each, O partial) ----
__global__ __launch_bounds__(256, 4) void attn_split_kernel(
    const float* __restrict__ Q, const float* __restrict__ K,
    const float* __restrict__ V, const u16* __restrict__ pmask,
    const float* __restrict__ lpart,
    float* __restrict__ op0, float* __restrict__ op1, float* __restrict__ score)
{
  const int bid = blockIdx.x;
  const int lid = (bid & 7) * (2048 / 8) + (bid >> 3);
  const int qt = lid & 31, kh = (lid >> 5) & 1, h = (lid >> 6) & 15, b = lid >> 10;
  attn_body<16>(Q, K, V, pmask, lpart, kh ? op1 : op0, score,
                b, h, qt, kh * 1024);
}

// ---- K2b: fallback full kernel (1024 blocks, full k, final O) ----
__global__ __launch_bounds__(256, 4) void attn_full_kernel(
    const float* __restrict__ Q, const float* __restrict__ K,
    const float* __restrict__ V, const u16* __restrict__ pmask,
    const float* __restrict__ lpart,
    float* __restrict__ out, float* __restrict__ score)
{
  const int bid = blockIdx.x;
  const int lid = (bid & 7) * (1024 / 8) + (bid >> 3);
  const int qt = lid & 31, h = (lid >> 5) & 15, b = lid >> 9;
  attn_body<32>(Q, K, V, pmask, lpart, out, score, b, h, qt, 0);
}

// ---------------- K3: out = op0 + op1 ----------------
__global__ __launch_bounds__(256) void combine_kernel(
    const float* __restrict__ op1, float* __restrict__ out)
{
  const int idx = blockIdx.x * 256 + threadIdx.x;   // f32x4 index
  f32x4 a = ((const f32x4*)out)[idx];
  f32x4 bq = ((const f32x4*)op1)[idx];
  a[0] += bq[0]; a[1] += bq[1]; a[2] += bq[2]; a[3] += bq[3];
  __builtin_nontemporal_store(a, (f32x4*)out + idx);
}

extern "C" void kernel_launch(void* const* d_in, const int* in_sizes, int n_in,
                              void* d_out, int out_size, void* d_ws, size_t ws_size,
                              hipStream_t stream) {
  const float* q = (const float*)d_in[0];
  const float* k = (const float*)d_in[1];
  const float* v = (const float*)d_in[2];
  const int* mask = (const int*)d_in[3];
  float* out = (float*)d_out;
  float* score = out + OUT_ELEMS;

  u16* pmask = (u16*)d_ws;                                  // 1 MB
  float* lpart = (float*)((char*)d_ws + (1 << 20));         // 1 MB
  float* op1 = (float*)((char*)d_ws + (2 << 20));           // 16.8 MB (optional)
  const size_t need = (size_t)(2 << 20) + OUT_ELEMS * sizeof(float);

  pack_kernel<<<dim3(B_ * L_ * WPR / 256), 256, 0, stream>>>(mask, pmask);
  lsum_kernel<<<dim3(32, 16, 8), 256, 0, stream>>>(q, k, pmask, lpart);
  if (ws_size >= need) {
    attn_split_kernel<<<dim3(2048), 256, 0, stream>>>(q, k, v, pmask, lpart,
                                                      out, op1, score);
    combine_kernel<<<dim3(OUT_ELEMS / 4 / 256), 256, 0, stream>>>(op1, out);
  } else {
    attn_full_kernel<<<dim3(1024), 256, 0, stream>>>(q, k, v, pmask, lpart,
                                                     out, score);
  }
}

// Round 23
// 217.864 us; speedup vs baseline: 1.8467x; 1.8467x over previous
//
#include <hip/hip_runtime.h>
#include <math.h>

#define B_ 2
#define H_ 16
#define L_ 2048
#define D_ 64
#define OUT_ELEMS ((size_t)B_ * H_ * L_ * D_)
#define WPR (L_ / 16)               // 128 mask-words per row
// SCALE * log2(e): scores computed directly in exp2 domain
#define C1 0.180336880f

typedef _Float16 half8 __attribute__((ext_vector_type(8)));
typedef _Float16 half4_t __attribute__((ext_vector_type(4)));
typedef float f32x4 __attribute__((ext_vector_type(4)));
typedef int i32x4 __attribute__((ext_vector_type(4)));
typedef unsigned int u32;
typedef unsigned short u16;
typedef u16 u16x4 __attribute__((ext_vector_type(4)));
typedef u32 u32x4 __attribute__((ext_vector_type(4)));
typedef u32 u32x2 __attribute__((ext_vector_type(2)));

// T2 XOR swizzle: 16B-slot permute within a 128B row (colh in halves)
#define SWZ(row, colh) ((colh) ^ (((row) & 7) << 3))

// ---------------- K0: pack mask -> 1 bit/element (1 MB table) ----------------
__global__ __launch_bounds__(256) void pack_kernel(
    const int* __restrict__ M, u16* __restrict__ pmask)
{
  const int idx = blockIdx.x * 256 + threadIdx.x;
  const int* src = M + (size_t)idx * 16;
  u32 w = 0;
#pragma unroll
  for (int j = 0; j < 4; ++j) {
    i32x4 m = ((const i32x4*)src)[j];
#pragma unroll
    for (int r = 0; r < 4; ++r)
      w |= (m[r] != 0 ? 1u : 0u) << (j * 4 + r);
  }
  pmask[idx] = (u16)w;
}

// -------- K1: flat-softmax denominators, k-split x4, 8 blocks/CU --------
// LDS-staged K (R22 showed direct global->reg->MFMA is 2x slower: no latency
// decoupling; stage-through-LDS beats direct-global even when L2-resident).
__global__ __launch_bounds__(256, 8) void lsum_kernel(
    const float* __restrict__ Q, const float* __restrict__ K,
    const u16* __restrict__ pmask, float* __restrict__ lpart)
{
  const int qt = blockIdx.x, h = blockIdx.y;
  const int b = blockIdx.z >> 2, kq = blockIdx.z & 3;
  const int bh = b * H_ + h;
  const int q0 = qt * 64, k0 = kq * 512;
  const int tid = threadIdx.x;
  const int wv = tid >> 6, lane = tid & 63;
  const int lr = lane & 15, lg = lane >> 4;
  const int qrow = q0 + wv * 16 + lr;

  __shared__ _Float16 Kbuf[64 * 64];   // 8KB single buffer

  const float* kbase = K + ((size_t)bh * L_ + k0) * D_;
  const u16* pmrow = pmask + (size_t)(b * L_ + qrow) * WPR + (k0 >> 4);

  half8 qf[2];
  {
    const float* qr = Q + (size_t)(bh * L_ + qrow) * D_;
#pragma unroll
    for (int f = 0; f < 2; ++f) {
      f32x4 x = *(const f32x4*)(qr + f * 32 + lg * 8);
      f32x4 y = *(const f32x4*)(qr + f * 32 + lg * 8 + 4);
      qf[f] = half8{(_Float16)(x[0]*C1), (_Float16)(x[1]*C1), (_Float16)(x[2]*C1), (_Float16)(x[3]*C1),
                    (_Float16)(y[0]*C1), (_Float16)(y[1]*C1), (_Float16)(y[2]*C1), (_Float16)(y[3]*C1)};
    }
  }

  const int ksr = tid >> 2, ksd = (tid & 3) * 16;
  float l_l = 0.f;

  for (int c = 0; c < 8; ++c) {
    const int kc = c * 64;
    f32x4 kr[4];
    {
      const float* s = kbase + (size_t)(kc + ksr) * D_ + ksd;
      kr[0] = ((const f32x4*)s)[0]; kr[1] = ((const f32x4*)s)[1];
      kr[2] = ((const f32x4*)s)[2]; kr[3] = ((const f32x4*)s)[3];
    }
    __syncthreads();   // chunk c-1 consumers done
    {
      half8 lo = half8{(_Float16)kr[0][0], (_Float16)kr[0][1], (_Float16)kr[0][2], (_Float16)kr[0][3],
                       (_Float16)kr[1][0], (_Float16)kr[1][1], (_Float16)kr[1][2], (_Float16)kr[1][3]};
      half8 hi = half8{(_Float16)kr[2][0], (_Float16)kr[2][1], (_Float16)kr[2][2], (_Float16)kr[2][3],
                       (_Float16)kr[3][0], (_Float16)kr[3][1], (_Float16)kr[3][2], (_Float16)kr[3][3]};
      *(half8*)&Kbuf[(ksr << 6) + SWZ(ksr, ksd)] = lo;
      *(half8*)&Kbuf[(ksr << 6) + SWZ(ksr, ksd + 8)] = hi;
    }
    __syncthreads();   // chunk c staged

    u16x4 pm = *(const u16x4*)(pmrow + c * 4);
    f32x4 acc[4] = {f32x4{0,0,0,0}, f32x4{0,0,0,0}, f32x4{0,0,0,0}, f32x4{0,0,0,0}};
    __builtin_amdgcn_s_setprio(1);
#pragma unroll
    for (int kb = 0; kb < 4; ++kb) {
      int row = kb * 16 + lr;
      half8 a0 = *(const half8*)&Kbuf[(row << 6) + SWZ(row, lg * 8)];
      half8 a1 = *(const half8*)&Kbuf[(row << 6) + SWZ(row, 32 + lg * 8)];
      acc[kb] = __builtin_amdgcn_mfma_f32_16x16x32_f16(a0, qf[0], acc[kb], 0, 0, 0);
      acc[kb] = __builtin_amdgcn_mfma_f32_16x16x32_f16(a1, qf[1], acc[kb], 0, 0, 0);
    }
    __builtin_amdgcn_s_setprio(0);

    float cs = 0.f;
#pragma unroll
    for (int kb = 0; kb < 4; ++kb)
#pragma unroll
      for (int r = 0; r < 4; ++r)
        cs += exp2f(((pm[kb] >> (lg * 4 + r)) & 1) ? acc[kb][r] : -INFINITY);
    l_l += cs;
  }

  l_l += __shfl_xor(l_l, 16);
  l_l += __shfl_xor(l_l, 32);
  if (lg == 0)
    lpart[((size_t)kq * 32 + bh) * L_ + qrow] = l_l;
}

// ------- K2 device body: score via LDS-coalesced NT stores + O partial -------
// Double-buffered K/V register prefetch. P tile bounced through swizzled Pbuf;
// each WAVE stores its OWN 16 rows (256B contiguous per row) -> no extra
// barrier (within-wave LDS RAW ordered by lgkmcnt).
template <int KCH>
__device__ __forceinline__ void attn_body(
    const float* Q, const float* K, const float* V,
    const u16* pmask, const float* lpart,
    float* obase, float* score, int b, int h, int qt, int k0)
{
  const int bh = b * H_ + h;
  const int q0 = qt * 64;
  const int tid = threadIdx.x;
  const int wv = tid >> 6, lane = tid & 63;
  const int lr = lane & 15, lg = lane >> 4;
  const int qrow = q0 + wv * 16 + lr;

  __shared__ _Float16 Klds[64 * 64];   // 8KB, XOR-swizzled
  __shared__ _Float16 Vlds[64 * 64];   // 8KB, XOR-swizzled
  __shared__ float Pbuf[64 * 68];      // 17KB, 17 f32x4-slots/row, swizzled

  const float* kbase = K + ((size_t)bh * L_ + k0) * D_;
  const float* vbase = V + ((size_t)bh * L_ + k0) * D_;
  const u16* pmrow = pmask + (size_t)(b * L_ + qrow) * WPR + (k0 >> 4);
  float* sbase = score + ((size_t)bh * L_ + q0) * L_ + k0;
  float* ob = obase + (size_t)(bh * L_ + q0) * D_;

  float lsum = 0.f;
#pragma unroll
  for (int kq = 0; kq < 4; ++kq)
    lsum += lpart[((size_t)kq * 32 + bh) * L_ + qrow];
  const float inv_l = (lsum > 0.f) ? 1.f / lsum : 0.f;

  half8 qf[2];
  {
    const float* qr = Q + (size_t)(bh * L_ + qrow) * D_;
#pragma unroll
    for (int f = 0; f < 2; ++f) {
      f32x4 x = *(const f32x4*)(qr + f * 32 + lg * 8);
      f32x4 y = *(const f32x4*)(qr + f * 32 + lg * 8 + 4);
      qf[f] = half8{(_Float16)(x[0]*C1), (_Float16)(x[1]*C1), (_Float16)(x[2]*C1), (_Float16)(x[3]*C1),
                    (_Float16)(y[0]*C1), (_Float16)(y[1]*C1), (_Float16)(y[2]*C1), (_Float16)(y[3]*C1)};
    }
  }

  const int ksr = tid >> 2, ksd = (tid & 3) * 16;
  const int vk0 = (tid & 15) * 4, vd0 = (tid >> 4) * 4;

  auto loadK4 = [&](int kc, f32x4* r) {
    const float* s = kbase + (size_t)(kc + ksr) * D_ + ksd;
    r[0] = ((const f32x4*)s)[0]; r[1] = ((const f32x4*)s)[1];
    r[2] = ((const f32x4*)s)[2]; r[3] = ((const f32x4*)s)[3];
  };
  auto writeK = [&](const f32x4* r) {
    half8 lo = half8{(_Float16)r[0][0], (_Float16)r[0][1], (_Float16)r[0][2], (_Float16)r[0][3],
                     (_Float16)r[1][0], (_Float16)r[1][1], (_Float16)r[1][2], (_Float16)r[1][3]};
    half8 hi = half8{(_Float16)r[2][0], (_Float16)r[2][1], (_Float16)r[2][2], (_Float16)r[2][3],
                     (_Float16)r[3][0], (_Float16)r[3][1], (_Float16)r[3][2], (_Float16)r[3][3]};
    *(half8*)&Klds[(ksr << 6) + SWZ(ksr, ksd)] = lo;
    *(half8*)&Klds[(ksr << 6) + SWZ(ksr, ksd + 8)] = hi;
  };
  auto loadV4 = [&](int kc, f32x4* r) {
#pragma unroll
    for (int i = 0; i < 4; ++i)
      r[i] = *(const f32x4*)(vbase + (size_t)(kc + vk0 + i) * D_ + vd0);
  };
  auto writeV = [&](const f32x4* r) {
#pragma unroll
    for (int j = 0; j < 4; ++j) {
      int row = vd0 + j;
      *(half4_t*)&Vlds[(row << 6) + SWZ(row, vk0)] =
          half4_t{(_Float16)r[0][j], (_Float16)r[1][j],
                  (_Float16)r[2][j], (_Float16)r[3][j]};
    }
  };

  {
    f32x4 kr[4], vr[4];
    loadK4(0, kr); loadV4(0, vr);
    writeK(kr); writeV(vr);
  }
  __syncthreads();

  f32x4 o_acc[4] = {f32x4{0,0,0,0}, f32x4{0,0,0,0}, f32x4{0,0,0,0}, f32x4{0,0,0,0}};
  f32x4 krP[4], vrP[4];

  const int s0lane = lr + 32 * (lg & 1);
  const int s1lane = s0lane + 16;
  const bool hisel = (lg & 2) != 0;

  for (int c = 0; c < KCH; ++c) {
    const int kc = c * 64;
    if (c > 0) {
      __syncthreads();            // K/V readers of chunk c-1 done
      writeK(krP);
      writeV(vrP);
      __syncthreads();            // chunk c staged
    }
    // prefetch next chunk into registers (consumed at next iter's top)
    if (c < KCH - 1) {
      loadK4(kc + 64, krP);
      loadV4(kc + 64, vrP);
    }
    u16x4 pm = *(const u16x4*)(pmrow + c * 4);

    f32x4 acc[4] = {f32x4{0,0,0,0}, f32x4{0,0,0,0}, f32x4{0,0,0,0}, f32x4{0,0,0,0}};
    __builtin_amdgcn_s_setprio(1);
#pragma unroll
    for (int kb = 0; kb < 4; ++kb) {
      int row = kb * 16 + lr;
      half8 a0 = *(const half8*)&Klds[(row << 6) + SWZ(row, lg * 8)];
      half8 a1 = *(const half8*)&Klds[(row << 6) + SWZ(row, 32 + lg * 8)];
      acc[kb] = __builtin_amdgcn_mfma_f32_16x16x32_f16(a0, qf[0], acc[kb], 0, 0, 0);
      acc[kb] = __builtin_amdgcn_mfma_f32_16x16x32_f16(a1, qf[1], acc[kb], 0, 0, 0);
    }
    __builtin_amdgcn_s_setprio(0);

    // P = exp2(s)/l ; stash fp32 tile in swizzled Pbuf; pack halves for PV
    u32 phu[8];
    const int prow = wv * 16 + lr;
#pragma unroll
    for (int kb = 0; kb < 4; ++kb) {
      f32x4 p4;
#pragma unroll
      for (int r = 0; r < 4; ++r)
        p4[r] = exp2f(((pm[kb] >> (lg * 4 + r)) & 1) ? acc[kb][r] : -INFINITY) * inv_l;
      int pslot = (kb * 4 + lg) ^ (prow & 7);           // 16B-slot swizzle
      *(f32x4*)&Pbuf[prow * 68 + pslot * 4] = p4;
      half4_t hp = half4_t{(_Float16)p4[0], (_Float16)p4[1],
                           (_Float16)p4[2], (_Float16)p4[3]};
      u32x2 uu = __builtin_bit_cast(u32x2, hp);
      phu[2 * kb] = uu[0];
      phu[2 * kb + 1] = uu[1];
    }

    // Redistribute P via shuffles; PV MFMA
    __builtin_amdgcn_s_setprio(1);
#pragma unroll
    for (int ks = 0; ks < 2; ++ks) {
      int a0 = __shfl((int)phu[4 * ks + 0], s0lane);
      int a1 = __shfl((int)phu[4 * ks + 1], s0lane);
      int a2 = __shfl((int)phu[4 * ks + 2], s0lane);
      int a3 = __shfl((int)phu[4 * ks + 3], s0lane);
      int b0 = __shfl((int)phu[4 * ks + 0], s1lane);
      int b1 = __shfl((int)phu[4 * ks + 1], s1lane);
      int b2 = __shfl((int)phu[4 * ks + 2], s1lane);
      int b3 = __shfl((int)phu[4 * ks + 3], s1lane);
      u32x4 pau = u32x4{(u32)(hisel ? a2 : a0), (u32)(hisel ? a3 : a1),
                        (u32)(hisel ? b2 : b0), (u32)(hisel ? b3 : b1)};
      half8 pa = __builtin_bit_cast(half8, pau);
#pragma unroll
      for (int db = 0; db < 4; ++db) {
        int row = db * 16 + lr;
        half8 vf = *(const half8*)&Vlds[(row << 6) + SWZ(row, ks * 32 + lg * 8)];
        o_acc[db] = __builtin_amdgcn_mfma_f32_16x16x32_f16(pa, vf, o_acc[db], 0, 0, 0);
      }
    }
    __builtin_amdgcn_s_setprio(0);

    // ---- per-wave coalesced score store (no barrier: own rows only) ----
#pragma unroll
    for (int it = 0; it < 4; ++it) {
      int row = wv * 16 + it * 4 + (lane >> 4);
      int slot = (lane & 15) ^ (row & 7);               // un-swizzle
      f32x4 v = *(const f32x4*)&Pbuf[row * 68 + slot * 4];
      __builtin_nontemporal_store(
          v, (f32x4*)(sbase + (size_t)row * L_ + kc + (lane & 15) * 4));
    }
  }

#pragma unroll
  for (int db = 0; db < 4; ++db)
#pragma unroll
    for (int r = 0; r < 4; ++r)
      ob[(size_t)(wv * 16 + lg * 4 + r) * D_ + db * 16 + lr] = o_acc[db][r];
}

// ---- K2a: split main kernel (2048 blocks, k-half each, O partial) ----
__global__ __launch_bounds__(256, 4) void attn_split_kernel(
    const float* __restrict__ Q, const float* __restrict__ K,
    const float* __restrict__ V, const u16* __restrict__ pmask,
    const float* __restrict__ lpart,
    float* __restrict__ op0, float* __restrict__ op1, float* __restrict__ score)
{
  const int bid = blockIdx.x;
  const int lid = (bid & 7) * (2048 / 8) + (bid >> 3);
  const int qt = lid & 31, kh = (lid >> 5) & 1, h = (lid >> 6) & 15, b = lid >> 10;
  attn_body<16>(Q, K, V, pmask, lpart, kh ? op1 : op0, score,
                b, h, qt, kh * 1024);
}

// ---- K2b: fallback full kernel (1024 blocks, full k, final O) ----
__global__ __launch_bounds__(256, 4) void attn_full_kernel(
    const float* __restrict__ Q, const float* __restrict__ K,
    const float* __restrict__ V, const u16* __restrict__ pmask,
    const float* __restrict__ lpart,
    float* __restrict__ out, float* __restrict__ score)
{
  const int bid = blockIdx.x;
  const int lid = (bid & 7) * (1024 / 8) + (bid >> 3);
  const int qt = lid & 31, h = (lid >> 5) & 15, b = lid >> 9;
  attn_body<32>(Q, K, V, pmask, lpart, out, score, b, h, qt, 0);
}

// ---------------- K3: out = op0 + op1 ----------------
__global__ __launch_bounds__(256) void combine_kernel(
    const float* __restrict__ op1, float* __restrict__ out)
{
  const int idx = blockIdx.x * 256 + threadIdx.x;   // f32x4 index
  f32x4 a = ((const f32x4*)out)[idx];
  f32x4 bq = ((const f32x4*)op1)[idx];
  a[0] += bq[0]; a[1] += bq[1]; a[2] += bq[2]; a[3] += bq[3];
  __builtin_nontemporal_store(a, (f32x4*)out + idx);
}

extern "C" void kernel_launch(void* const* d_in, const int* in_sizes, int n_in,
                              void* d_out, int out_size, void* d_ws, size_t ws_size,
                              hipStream_t stream) {
  const float* q = (const float*)d_in[0];
  const float* k = (const float*)d_in[1];
  const float* v = (const float*)d_in[2];
  const int* mask = (const int*)d_in[3];
  float* out = (float*)d_out;
  float* score = out + OUT_ELEMS;

  u16* pmask = (u16*)d_ws;                                  // 1 MB
  float* lpart = (float*)((char*)d_ws + (1 << 20));         // 1 MB
  float* op1 = (float*)((char*)d_ws + (2 << 20));           // 16.8 MB (optional)
  const size_t need = (size_t)(2 << 20) + OUT_ELEMS * sizeof(float);

  pack_kernel<<<dim3(B_ * L_ * WPR / 256), 256, 0, stream>>>(mask, pmask);
  lsum_kernel<<<dim3(32, 16, 8), 256, 0, stream>>>(q, k, pmask, lpart);
  if (ws_size >= need) {
    attn_split_kernel<<<dim3(2048), 256, 0, stream>>>(q, k, v, pmask, lpart,
                                                      out, op1, score);
    combine_kernel<<<dim3(OUT_ELEMS / 4 / 256), 256, 0, stream>>>(op1, out);
  } else {
    attn_full_kernel<<<dim3(1024), 256, 0, stream>>>(q, k, v, pmask, lpart,
                                                     out, score);
  }
}